// Round 3
// baseline (499.682 us; speedup 1.0000x reference)
//
#include <hip/hip_runtime.h>

// Problem constants: B=4, S=2048, D=1024, H=16, DK=64
#define BDIM 4
#define SDIM 2048
#define DDIM 1024
#define HDIM 16
#define DKDIM 64
#define MDIM (BDIM*SDIM)   // 8192

typedef __attribute__((ext_vector_type(8))) short bf16x8_t;
typedef __attribute__((ext_vector_type(4))) float f32x4_t;

__device__ __forceinline__ unsigned short f2bf(float f) {
    union { float f; unsigned u; } v; v.f = f;
    unsigned r = v.u + 0x7FFFu + ((v.u >> 16) & 1u);  // RNE
    return (unsigned short)(r >> 16);
}

__device__ __forceinline__ unsigned pkbf(float a, float b) {
#if defined(__has_builtin) && __has_builtin(__builtin_amdgcn_cvt_pk_bf16_f32)
    auto v = __builtin_amdgcn_cvt_pk_bf16_f32(a, b);
    union { decltype(v) x; unsigned u; } cv; cv.x = v; return cv.u;
#else
    return (unsigned)f2bf(a) | ((unsigned)f2bf(b) << 16);
#endif
}

#if defined(__has_builtin) && __has_builtin(__builtin_amdgcn_exp2f)
#define EXP2F(x) __builtin_amdgcn_exp2f(x)
#else
#define EXP2F(x) __expf((x) * 0.69314718f)
#endif

#define QSCALE 0.18033688011112042f  // log2(e)/8, folded into Q projection

__device__ __forceinline__ void gl_lds16(const void* g, void* l) {
    __builtin_amdgcn_global_load_lds(
        (const __attribute__((address_space(1))) unsigned int*)g,
        (__attribute__((address_space(3))) unsigned int*)l, 16, 0, 0);
}

// ---------------- fp32 -> bf16 casts (batched) ----------------
__global__ void cvt3(const float* __restrict__ a, const float* __restrict__ b, const float* __restrict__ c,
                     unsigned short* __restrict__ oa, unsigned short* __restrict__ ob, unsigned short* __restrict__ oc,
                     int n4) {
    int i = blockIdx.x * blockDim.x + threadIdx.x;
    const float* s = blockIdx.y == 0 ? a : (blockIdx.y == 1 ? b : c);
    unsigned short* d = blockIdx.y == 0 ? oa : (blockIdx.y == 1 ? ob : oc);
    if (i < n4) {
        float4 v = ((const float4*)s)[i];
        ushort4 o;
        o.x = f2bf(v.x); o.y = f2bf(v.y); o.z = f2bf(v.z); o.w = f2bf(v.w);
        ((ushort4*)d)[i] = o;
    }
}

__global__ void cvt4(const float* __restrict__ a, const float* __restrict__ b,
                     const float* __restrict__ c, const float* __restrict__ e,
                     unsigned short* __restrict__ oa, unsigned short* __restrict__ ob,
                     unsigned short* __restrict__ oc, unsigned short* __restrict__ oe,
                     int n4) {
    int i = blockIdx.x * blockDim.x + threadIdx.x;
    const float* s = blockIdx.y == 0 ? a : (blockIdx.y == 1 ? b : (blockIdx.y == 2 ? c : e));
    unsigned short* d = blockIdx.y == 0 ? oa : (blockIdx.y == 1 ? ob : (blockIdx.y == 2 ? oc : oe));
    if (i < n4) {
        float4 v = ((const float4*)s)[i];
        ushort4 o;
        o.x = f2bf(v.x); o.y = f2bf(v.y); o.z = f2bf(v.z); o.w = f2bf(v.w);
        ((ushort4*)d)[i] = o;
    }
}

// ---------------- mask -> bitmask (1 bit per key) ----------------
__global__ void pack_mask(const int* __restrict__ m, unsigned long long* __restrict__ bits) {
    int g = blockIdx.x * 256 + threadIdx.x;
    unsigned long long bal = __ballot(m[g] != 0);
    if ((threadIdx.x & 63) == 0) bits[g >> 6] = bal;
}

// ---------------- NT GEMM: C[M,N] = (A[M,K] @ B[N,K]^T + bias) * scale ----------------
// OMODE 0: bf16 out row-major; 1: bf16 out transposed (C^T, [N][M]); 2: f32 out row-major
template<int OMODE>
__global__ __launch_bounds__(256) void gemm_nt(
    const unsigned short* __restrict__ A,
    const unsigned short* __restrict__ B,
    const float* __restrict__ bias,
    unsigned short* __restrict__ Cb,
    float* __restrict__ Cf,
    int M, int N, int K, float scale)
{
    __shared__ unsigned short As[128 * 32];
    __shared__ unsigned short Bs[128 * 32];
    const int tid = threadIdx.x;
    const int w = tid >> 6, lane = tid & 63;
    const int wr = w >> 1, wc = w & 1;
    const int quad = lane >> 4, l16 = lane & 15;
    const int bn = blockIdx.x, bm = blockIdx.y;

    const int rl = lane >> 2, cl = (lane & 3) * 8;
    const int c0 = w * 2;
    const unsigned short* gA = A + (size_t)(bm * 128 + c0 * 16 + rl) * K + cl;
    const unsigned short* gB = B + (size_t)(bn * 128 + c0 * 16 + rl) * K + cl;
    unsigned short* lA = As + c0 * 512 + lane * 8;
    unsigned short* lB = Bs + c0 * 512 + lane * 8;

    f32x4_t acc[4][4] = {};

    for (int k0 = 0; k0 < K; k0 += 32) {
        gl_lds16(gA, lA);
        gl_lds16(gA + (size_t)16 * K, lA + 16 * 32);
        gl_lds16(gB, lB);
        gl_lds16(gB + (size_t)16 * K, lB + 16 * 32);
        gA += 32; gB += 32;
        __syncthreads();
        bf16x8_t af[4], bfr[4];
#pragma unroll
        for (int mi = 0; mi < 4; ++mi)
            af[mi] = *(const bf16x8_t*)(As + (wr * 64 + mi * 16 + l16) * 32 + quad * 8);
#pragma unroll
        for (int ni = 0; ni < 4; ++ni)
            bfr[ni] = *(const bf16x8_t*)(Bs + (wc * 64 + ni * 16 + l16) * 32 + quad * 8);
#pragma unroll
        for (int mi = 0; mi < 4; ++mi)
#pragma unroll
            for (int ni = 0; ni < 4; ++ni)
                acc[mi][ni] = __builtin_amdgcn_mfma_f32_16x16x32_bf16(af[mi], bfr[ni], acc[mi][ni], 0, 0, 0);
        __syncthreads();
    }

#pragma unroll
    for (int mi = 0; mi < 4; ++mi) {
#pragma unroll
        for (int ni = 0; ni < 4; ++ni) {
            const int n = bn * 128 + wc * 64 + ni * 16 + l16;
            const int m0 = bm * 128 + wr * 64 + mi * 16 + quad * 4;
            const float bv = bias[n];
            if (OMODE == 1) {
                ushort4 pk;
                pk.x = f2bf((acc[mi][ni][0] + bv) * scale);
                pk.y = f2bf((acc[mi][ni][1] + bv) * scale);
                pk.z = f2bf((acc[mi][ni][2] + bv) * scale);
                pk.w = f2bf((acc[mi][ni][3] + bv) * scale);
                *(ushort4*)(Cb + (size_t)n * M + m0) = pk;
            } else {
#pragma unroll
                for (int r = 0; r < 4; ++r) {
                    const float v = (acc[mi][ni][r] + bv) * scale;
                    if (OMODE == 0) Cb[(size_t)(m0 + r) * N + n] = f2bf(v);
                    else            Cf[(size_t)(m0 + r) * N + n] = v;
                }
            }
        }
    }
}

// ---------------- fused flash attention (fixed-max softmax, 128-row q-tile) ----------------
// Block: 256 threads / 4 waves; wave w handles q-rows w*32..w*32+31 (2 row-groups).
__global__ __launch_bounds__(256) void attn_kernel(
    const unsigned short* __restrict__ Qp,   // [M][D] bf16, pre-scaled by log2e/8
    const unsigned short* __restrict__ Kp,   // [M][D] bf16
    const unsigned short* __restrict__ Vt,   // [D][M] bf16 (V^T)
    const unsigned long long* __restrict__ mbits, // [B*S][32] packed mask bits
    unsigned short* __restrict__ Xa)         // [M][D] bf16
{
    __shared__ unsigned short Ks[2 * 64 * 32];           // 8 KB  (also Q-stage cols 0-31)
    __shared__ unsigned short Vs[2 * 64 * 32];           // 8 KB  (also Q-stage cols 32-63)
    __shared__ __align__(16) float Pf[4][2][2][16][36];  // per-wave/per-group P (f32), 36 KB

    const int tid = threadIdx.x, w = tid >> 6, lane = tid & 63;
    const int quad = lane >> 4, l16 = lane & 15;
    const int bx = blockIdx.x;
    const int h = bx & 15, qt = (bx >> 4) & 15, b = bx >> 8;
    const int q0 = qt * 128;
    const int rl = lane >> 2, cl = (lane & 3) * 8;

    // ---- stage 128x64 Q tile through LDS, pull A-frags to registers ----
#pragma unroll
    for (int i = 0; i < 4; ++i) {
        const int cc = w * 4 + i;
        const int row = b * SDIM + q0 + (cc & 7) * 16 + rl;
        const int col = h * 64 + (cc >> 3) * 32 + cl;
        unsigned short* dst = (cc < 8 ? Ks + cc * 512 : Vs + (cc - 8) * 512) + lane * 8;
        gl_lds16(Qp + (size_t)row * DDIM + col, dst);
    }
    __syncthreads();
    bf16x8_t aq[2][2];  // [row-group g][kk]
#pragma unroll
    for (int g = 0; g < 2; ++g) {
        aq[g][0] = *(const bf16x8_t*)(Ks + (w * 2 + g) * 512 + l16 * 32 + quad * 8);
        aq[g][1] = *(const bf16x8_t*)(Vs + (w * 2 + g) * 512 + l16 * 32 + quad * 8);
    }

    const unsigned long long* mp =
        mbits + (size_t)(b * SDIM + q0 + w * 32 + quad * 4) * 32;

    f32x4_t o[2][4] = {};
    f32x4_t o4[2] = {};
    union { unsigned u[4]; bf16x8_t v; } ones;
    ones.u[0] = ones.u[1] = ones.u[2] = ones.u[3] = 0x3F803F80u;

    for (int kt = 0; kt < SDIM / 64; ++kt) {
        __syncthreads();   // prior-iter LDS reads done (incl. Q reg pull at kt=0)
#pragma unroll
        for (int i = 0; i < 2; ++i) {
            const int cc = w * 2 + i;
            const int rowk = b * SDIM + kt * 64 + (cc & 3) * 16 + rl;
            const int colk = h * 64 + (cc >> 2) * 32 + cl;
            gl_lds16(Kp + (size_t)rowk * DDIM + colk, Ks + cc * 512 + lane * 8);
            const int rowv = h * 64 + (cc & 3) * 16 + rl;
            const int colv = b * SDIM + kt * 64 + (cc >> 2) * 32 + cl;
            gl_lds16(Vt + (size_t)rowv * MDIM + colv, Vs + cc * 512 + lane * 8);
        }
        __syncthreads();

        // mask bits (one 8B broadcast load per row-group x row)
        unsigned long long mb[2][4];
#pragma unroll
        for (int g = 0; g < 2; ++g)
#pragma unroll
            for (int r = 0; r < 4; ++r) mb[g][r] = mp[g * 512 + r * 32 + kt];

        // S = Q K^T (K frags shared by both row-groups)
        f32x4_t sf[2][4] = {};
#pragma unroll
        for (int kk = 0; kk < 2; ++kk) {
#pragma unroll
            for (int ni = 0; ni < 4; ++ni) {
                const bf16x8_t bk = *(const bf16x8_t*)(Ks + kk * 2048 + (ni * 16 + l16) * 32 + quad * 8);
                sf[0][ni] = __builtin_amdgcn_mfma_f32_16x16x32_bf16(aq[0][kk], bk, sf[0][ni], 0, 0, 0);
                sf[1][ni] = __builtin_amdgcn_mfma_f32_16x16x32_bf16(aq[1][kk], bk, sf[1][ni], 0, 0, 0);
            }
        }

        // p = exp2(s) (Q pre-scaled), masked -> 0; P to per-wave LDS (f32, C-layout)
#pragma unroll
        for (int g = 0; g < 2; ++g) {
#pragma unroll
            for (int r = 0; r < 4; ++r) {
                const unsigned long long sh = mb[g][r] >> l16;
                const unsigned mlo = (unsigned)sh;
                const unsigned mhi = (unsigned)(sh >> 32);
                const int row = quad * 4 + r;
                const float t0 = (mlo & 1u)         ? sf[g][0][r] : -INFINITY;
                const float t1 = ((mlo >> 16) & 1u) ? sf[g][1][r] : -INFINITY;
                const float t2 = (mhi & 1u)         ? sf[g][2][r] : -INFINITY;
                const float t3 = ((mhi >> 16) & 1u) ? sf[g][3][r] : -INFINITY;
                Pf[w][g][0][row][l16]      = EXP2F(t0);
                Pf[w][g][0][row][16 + l16] = EXP2F(t1);
                Pf[w][g][1][row][l16]      = EXP2F(t2);
                Pf[w][g][1][row][16 + l16] = EXP2F(t3);
            }
        }

        // P (C-layout) -> A-frags via per-wave LDS; PV + ones-column row-sum
#pragma unroll
        for (int kk = 0; kk < 2; ++kk) {
            bf16x8_t bvf[4];
#pragma unroll
            for (int ni = 0; ni < 4; ++ni)
                bvf[ni] = *(const bf16x8_t*)(Vs + kk * 2048 + (ni * 16 + l16) * 32 + quad * 8);
#pragma unroll
            for (int g = 0; g < 2; ++g) {
                const float* pr = &Pf[w][g][kk][l16][quad * 8];
                const float4 pa = *(const float4*)pr;
                const float4 pb = *(const float4*)(pr + 4);
                union { unsigned u[4]; bf16x8_t v; } fu;
                fu.u[0] = pkbf(pa.x, pa.y);
                fu.u[1] = pkbf(pa.z, pa.w);
                fu.u[2] = pkbf(pb.x, pb.y);
                fu.u[3] = pkbf(pb.z, pb.w);
#pragma unroll
                for (int ni = 0; ni < 4; ++ni)
                    o[g][ni] = __builtin_amdgcn_mfma_f32_16x16x32_bf16(fu.v, bvf[ni], o[g][ni], 0, 0, 0);
                o4[g] = __builtin_amdgcn_mfma_f32_16x16x32_bf16(fu.v, ones.v, o4[g], 0, 0, 0);
            }
        }
    }

    // finalize: l = o4[g][r] (every column of ones-tile = row sum; no reduce needed)
#pragma unroll
    for (int g = 0; g < 2; ++g) {
        float rcp[4];
#pragma unroll
        for (int r = 0; r < 4; ++r) rcp[r] = 1.0f / o4[g][r];
#pragma unroll
        for (int ni = 0; ni < 4; ++ni)
#pragma unroll
            for (int r = 0; r < 4; ++r) {
                const int qg = q0 + w * 32 + g * 16 + quad * 4 + r;
                const int cg = h * 64 + ni * 16 + l16;
                Xa[((size_t)b * SDIM + qg) * DDIM + cg] = f2bf(o[g][ni][r] * rcp[r]);
            }
    }
}

extern "C" void kernel_launch(void* const* d_in, const int* in_sizes, int n_in,
                              void* d_out, int out_size, void* d_ws, size_t ws_size,
                              hipStream_t stream)
{
    const float* query = (const float*)d_in[0];
    const float* key   = (const float*)d_in[1];
    const float* value = (const float*)d_in[2];
    const int*   mask  = (const int*)d_in[3];
    const float* Wq = (const float*)d_in[4];  const float* bq = (const float*)d_in[5];
    const float* Wk = (const float*)d_in[6];  const float* bk = (const float*)d_in[7];
    const float* Wv = (const float*)d_in[8];  const float* bv = (const float*)d_in[9];
    const float* Wo = (const float*)d_in[10]; const float* bo = (const float*)d_in[11];

    const size_t MD = (size_t)MDIM * DDIM;
    const size_t DD = (size_t)DDIM * DDIM;

    unsigned short* qb  = (unsigned short*)d_ws;
    unsigned short* kb  = qb + MD;
    unsigned short* vb  = kb + MD;
    unsigned short* wqb = vb + MD;
    unsigned short* wkb = wqb + DD;
    unsigned short* wvb = wkb + DD;
    unsigned short* wob = wvb + DD;
    unsigned short* Qp  = wob + DD;
    unsigned short* Kp  = Qp + MD;
    unsigned short* Vt  = Kp + MD;
    unsigned short* Xa  = Vt + MD;
    unsigned long long* mbits = (unsigned long long*)qb;  // reuse after Q GEMM

    {
        const int n4m = (int)(MD / 4), n4d = (int)(DD / 4);
        dim3 g3((n4m + 255) / 256, 3), g4((n4d + 255) / 256, 4);
        cvt3<<<g3, 256, 0, stream>>>(query, key, value, qb, kb, vb, n4m);
        cvt4<<<g4, 256, 0, stream>>>(Wq, Wk, Wv, Wo, wqb, wkb, wvb, wob, n4d);
    }

    dim3 gg(DDIM / 128, MDIM / 128);
    gemm_nt<0><<<gg, 256, 0, stream>>>(qb, wqb, bq, Qp, nullptr, MDIM, DDIM, DDIM, QSCALE);
    gemm_nt<0><<<gg, 256, 0, stream>>>(kb, wkb, bk, Kp, nullptr, MDIM, DDIM, DDIM, 1.0f);
    gemm_nt<1><<<gg, 256, 0, stream>>>(vb, wvb, bv, Vt, nullptr, MDIM, DDIM, DDIM, 1.0f);

    pack_mask<<<(BDIM * SDIM * SDIM) / 256, 256, 0, stream>>>(mask, mbits);

    attn_kernel<<<BDIM * HDIM * (SDIM / 128), 256, 0, stream>>>(Qp, Kp, Vt, mbits, Xa);

    gemm_nt<2><<<gg, 256, 0, stream>>>(Xa, wob, bo, nullptr, (float*)d_out, MDIM, DDIM, DDIM, 1.0f);
}